// Round 4
// baseline (396.201 us; speedup 1.0000x reference)
//
#include <hip/hip_runtime.h>
#include <cstdint>
#include <cstddef>

typedef unsigned short u16;
typedef short bf16x8 __attribute__((ext_vector_type(8)));
typedef float floatx4 __attribute__((ext_vector_type(4)));

#define GLD16(gp, sp) __builtin_amdgcn_global_load_lds(                      \
    (const __attribute__((address_space(1))) void*)(gp),                     \
    (__attribute__((address_space(3))) void*)(sp), 16, 0, 0)

__device__ __forceinline__ u16 f2bf(float f) {
  unsigned u = __float_as_uint(f);
  u += 0x7fffu + ((u >> 16) & 1u);   // round-to-nearest-even
  return (u16)(u >> 16);
}

// ---------------- fused prep ----------------
// regions: [0,1024) cvt_x | [1024,9216) w1^T | [9216,13312) w2^T | [13312,13824) router+scatter
__global__ __launch_bounds__(256) void prep_kernel(
    const float* __restrict__ x, const float* __restrict__ rw, const float* __restrict__ rbias,
    const float* __restrict__ w1, const float* __restrict__ w2,
    u16* __restrict__ xb, u16* __restrict__ w1t, u16* __restrict__ w2t,
    float* __restrict__ ew, int* __restrict__ row_token, float* __restrict__ row_scale,
    int* __restrict__ cnt) {
  __shared__ float lds[64 * 33];
  const int b = blockIdx.x, tid = threadIdx.x;
  if (b < 1024) {                       // ---- x f32 -> bf16
    const float4* in4 = (const float4*)x;
    ushort4* out4 = (ushort4*)xb;
    int i = (b << 8) + tid;
#pragma unroll
    for (int rep = 0; rep < 2; ++rep, i += 262144) {
      float4 v = in4[i];
      ushort4 o;
      o.x = f2bf(v.x); o.y = f2bf(v.y); o.z = f2bf(v.z); o.w = f2bf(v.w);
      out4[i] = o;
    }
  } else if (b < 13312) {               // ---- weight transpose+cvt (64r x 32c tiles)
    const float* in; u16* out; int C, r0, c0;
    if (b < 9216) {
      int b2 = b - 1024, e = b2 >> 10, rem = b2 & 1023;   // 16 r-tiles x 64 c-tiles
      C = 2048; r0 = (rem >> 6) << 6; c0 = (rem & 63) << 5;
      in = w1 + (size_t)e * 2097152; out = w1t + (size_t)e * 2097152;
    } else {
      int b2 = b - 9216, e = b2 >> 9, rem = b2 & 511;     // 16 r-tiles x 32 c-tiles
      C = 1024; r0 = (rem >> 5) << 6; c0 = (rem & 31) << 5;
      in = w2 + (size_t)e * 1048576; out = w2t + (size_t)e * 1048576;
    }
    const int tx = tid & 31, ty = tid >> 5;
#pragma unroll
    for (int k = 0; k < 8; ++k) {
      int row = k * 8 + ty;
      lds[row * 33 + tx] = in[(size_t)(r0 + row) * C + c0 + tx];
    }
    __syncthreads();
#pragma unroll
    for (int k = 0; k < 4; ++k) {
      int cc = k * 8 + ty;
      ushort2 v;
      v.x = f2bf(lds[(tx * 2) * 33 + cc]);
      v.y = f2bf(lds[(tx * 2 + 1) * 33 + cc]);
      *(ushort2*)(out + (size_t)(c0 + cc) * 1024 + r0 + tx * 2) = v;
    }
  } else {                              // ---- router (4 tokens/block) + direct scatter
    const int wave = tid >> 6, lane = tid & 63;
    const int t = ((b - 13312) << 2) + wave;
    const float4* xv = (const float4*)(x + (size_t)t * 1024);
    float acc[8];
#pragma unroll
    for (int e = 0; e < 8; ++e) acc[e] = 0.f;
    for (int j = lane; j < 256; j += 64) {
      float4 xx = xv[j];
#pragma unroll
      for (int e = 0; e < 8; ++e) {
        float4 wv = ((const float4*)(rw + (size_t)e * 1024))[j];
        acc[e] += xx.x * wv.x + xx.y * wv.y + xx.z * wv.z + xx.w * wv.w;
      }
    }
#pragma unroll
    for (int e = 0; e < 8; ++e) {
      float v = acc[e];
#pragma unroll
      for (int off = 32; off > 0; off >>= 1) v += __shfl_down(v, off);
      acc[e] = v;
    }
    if (lane == 0) {
      float p[8];
      float mx = -1e30f;
#pragma unroll
      for (int e = 0; e < 8; ++e) { p[e] = acc[e] + rbias[e]; mx = fmaxf(mx, p[e]); }
      float sum = 0.f;
#pragma unroll
      for (int e = 0; e < 8; ++e) { p[e] = __expf(p[e] - mx); sum += p[e]; }
      float inv = 1.f / sum;
#pragma unroll
      for (int e = 0; e < 8; ++e) p[e] *= inv;
      int i0 = 0;
#pragma unroll
      for (int e = 1; e < 8; ++e) if (p[e] > p[i0]) i0 = e;
      int i1 = (i0 == 0) ? 1 : 0;
#pragma unroll
      for (int e = 0; e < 8; ++e) if (e != i0 && e != i1 && p[e] > p[i1]) i1 = e;
      ew[t * 2 + 0] = p[i0];
      ew[t * 2 + 1] = p[i1];
      int s0 = atomicAdd(&cnt[i0], 1);           // device-scope; fixed 2048-slot region/expert
      row_token[(i0 << 11) + s0] = t;
      row_scale[(i0 << 11) + s0] = p[i0];
      int s1 = atomicAdd(&cnt[i1], 1);
      row_token[(i1 << 11) + s1] = t;
      row_scale[(i1 << 11) + s1] = p[i1];
    }
  }
}

// ---------------- GEMM1: 128x128 tile, BK=64, gathered rows, glu epilogue -> actS ----
// grid 2048: d -> xcd=d&7, j=d>>3: colHi=j&1, rb=(j>>1)&15, e=j>>5. colIdx=xcd+8*colHi.
// LDS chunk-major: group g (16 rows x 64 k = 2 KiB) at g*1024 u16; half h at +h*512;
// frag read = base + lane*8 u16 -> conflict-free ds_read_b128.
__global__ __launch_bounds__(256) void gemm1_act_kernel(
    const u16* __restrict__ xb, const u16* __restrict__ w1t,
    const float* __restrict__ w1b,
    const int* __restrict__ row_token, const float* __restrict__ row_scale,
    const int* __restrict__ cnt, u16* __restrict__ actS) {
  const int d = blockIdx.x;
  const int xcd = d & 7, j = d >> 3;
  const int colHi = j & 1, rb = (j >> 1) & 15, e = j >> 5;
  if (rb * 128 >= cnt[e]) return;
  const int colBase = (xcd + (colHi << 3)) << 7;
  const int slotB = (e << 11) + (rb << 7);
  __shared__ __align__(16) u16 As[128 * 64];
  __shared__ __align__(16) u16 Bs[128 * 64];
  const int tid = threadIdx.x, lane = tid & 63, wave = tid >> 6;
  const int row16 = lane & 15, chunk = lane >> 4;
  const u16* Bt = w1t + (size_t)e * 2097152;
  const int g0 = wave * 2, g1 = wave * 2 + 1;
  int tk0 = row_token[slotB + g0 * 16 + row16];   // pads are token 0 (harmless, scale 0)
  int tk1 = row_token[slotB + g1 * 16 + row16];
  const u16* aP0 = xb + (size_t)tk0 * 1024 + chunk * 8;
  const u16* aP1 = xb + (size_t)tk1 * 1024 + chunk * 8;
  const u16* bP0 = Bt + (size_t)(colBase + g0 * 16 + row16) * 1024 + chunk * 8;
  const u16* bP1 = Bt + (size_t)(colBase + g1 * 16 + row16) * 1024 + chunk * 8;
  const int wr = wave >> 1, wc = wave & 1;
  floatx4 acc[4][4];
#pragma unroll
  for (int mi = 0; mi < 4; ++mi)
#pragma unroll
    for (int ni = 0; ni < 4; ++ni) acc[mi][ni] = floatx4{0.f, 0.f, 0.f, 0.f};

  for (int kt = 0; kt < 16; ++kt) {
    const int k = kt * 64;
    GLD16(aP0 + k,      As + g0 * 1024);
    GLD16(aP0 + k + 32, As + g0 * 1024 + 512);
    GLD16(aP1 + k,      As + g1 * 1024);
    GLD16(aP1 + k + 32, As + g1 * 1024 + 512);
    GLD16(bP0 + k,      Bs + g0 * 1024);
    GLD16(bP0 + k + 32, Bs + g0 * 1024 + 512);
    GLD16(bP1 + k,      Bs + g1 * 1024);
    GLD16(bP1 + k + 32, Bs + g1 * 1024 + 512);
    __syncthreads();
#pragma unroll
    for (int kh = 0; kh < 2; ++kh) {
      bf16x8 af[4], bfr[4];
#pragma unroll
      for (int mi = 0; mi < 4; ++mi)
        af[mi] = *(const bf16x8*)(As + (wr * 4 + mi) * 1024 + kh * 512 + lane * 8);
#pragma unroll
      for (int ni = 0; ni < 4; ++ni)
        bfr[ni] = *(const bf16x8*)(Bs + (wc * 4 + ni) * 1024 + kh * 512 + lane * 8);
#pragma unroll
      for (int mi = 0; mi < 4; ++mi)
#pragma unroll
        for (int ni = 0; ni < 4; ++ni)
          acc[mi][ni] = __builtin_amdgcn_mfma_f32_16x16x32_bf16(af[mi], bfr[ni], acc[mi][ni], 0, 0, 0);
    }
    __syncthreads();
  }

  const int cl = lane & 15, ql = lane >> 4;
#pragma unroll
  for (int mi = 0; mi < 4; ++mi) {
#pragma unroll
    for (int r = 0; r < 4; ++r) {
      const int slot = slotB + wr * 64 + mi * 16 + ql * 4 + r;
      const float c = row_scale[slot];  // 0 for padded slots -> zero fill
#pragma unroll
      for (int ni = 0; ni < 4; ++ni) {
        const int n = colBase + wc * 64 + ni * 16 + cl;  // interleaved col of w1
        float v = acc[mi][ni][r] + w1b[e * 2048 + n];
        float o = __shfl_xor(v, 1);  // partner column
        if ((lane & 1) == 0) {       // even lane = gate col
          float g = fminf(v, 7.f);
          float u = fminf(fmaxf(o, -7.f), 7.f);
          float sg = 1.f / (1.f + __expf(-1.702f * g));
          float a = (u + 1.f) * (g * sg);
          actS[(size_t)slot * 1024 + (n >> 1)] = f2bf(c * a);
        }
      }
    }
  }
}

// ---------------- GEMM2: 128x128, BK=64, split-K=2, bias folded, atomic scatter ----
// grid 2048: d -> xcd=d&7 (=colIdx over 8 tiles), j=d>>3: ks=j&1, rb=(j>>1)&15, e=j>>5.
__global__ __launch_bounds__(256) void gemm2_add_kernel(
    const u16* __restrict__ actS, const u16* __restrict__ w2t, const float* __restrict__ w2b,
    const int* __restrict__ row_token, const float* __restrict__ row_scale,
    const int* __restrict__ cnt, float* __restrict__ out) {
  const int d = blockIdx.x;
  const int xcd = d & 7, j = d >> 3;
  const int ks = j & 1, rb = (j >> 1) & 15, e = j >> 5;
  if (rb * 128 >= cnt[e]) return;
  const int colBase = xcd << 7;
  const int slotB = (e << 11) + (rb << 7);
  const int k0 = ks << 9;
  __shared__ __align__(16) u16 As[128 * 64];
  __shared__ __align__(16) u16 Bs[128 * 64];
  const int tid = threadIdx.x, lane = tid & 63, wave = tid >> 6;
  const int row16 = lane & 15, chunk = lane >> 4;
  const u16* Bt = w2t + (size_t)e * 1048576;
  const int g0 = wave * 2, g1 = wave * 2 + 1;
  const u16* aP0 = actS + (size_t)(slotB + g0 * 16 + row16) * 1024 + chunk * 8;
  const u16* aP1 = actS + (size_t)(slotB + g1 * 16 + row16) * 1024 + chunk * 8;
  const u16* bP0 = Bt + (size_t)(colBase + g0 * 16 + row16) * 1024 + chunk * 8;
  const u16* bP1 = Bt + (size_t)(colBase + g1 * 16 + row16) * 1024 + chunk * 8;
  const int wr = wave >> 1, wc = wave & 1;
  floatx4 acc[4][4];
#pragma unroll
  for (int mi = 0; mi < 4; ++mi)
#pragma unroll
    for (int ni = 0; ni < 4; ++ni) acc[mi][ni] = floatx4{0.f, 0.f, 0.f, 0.f};

  for (int kt = 0; kt < 8; ++kt) {
    const int k = k0 + kt * 64;
    GLD16(aP0 + k,      As + g0 * 1024);
    GLD16(aP0 + k + 32, As + g0 * 1024 + 512);
    GLD16(aP1 + k,      As + g1 * 1024);
    GLD16(aP1 + k + 32, As + g1 * 1024 + 512);
    GLD16(bP0 + k,      Bs + g0 * 1024);
    GLD16(bP0 + k + 32, Bs + g0 * 1024 + 512);
    GLD16(bP1 + k,      Bs + g1 * 1024);
    GLD16(bP1 + k + 32, Bs + g1 * 1024 + 512);
    __syncthreads();
#pragma unroll
    for (int kh = 0; kh < 2; ++kh) {
      bf16x8 af[4], bfr[4];
#pragma unroll
      for (int mi = 0; mi < 4; ++mi)
        af[mi] = *(const bf16x8*)(As + (wr * 4 + mi) * 1024 + kh * 512 + lane * 8);
#pragma unroll
      for (int ni = 0; ni < 4; ++ni)
        bfr[ni] = *(const bf16x8*)(Bs + (wc * 4 + ni) * 1024 + kh * 512 + lane * 8);
#pragma unroll
      for (int mi = 0; mi < 4; ++mi)
#pragma unroll
        for (int ni = 0; ni < 4; ++ni)
          acc[mi][ni] = __builtin_amdgcn_mfma_f32_16x16x32_bf16(af[mi], bfr[ni], acc[mi][ni], 0, 0, 0);
    }
    __syncthreads();
  }

  const int cl = lane & 15, ql = lane >> 4;
#pragma unroll
  for (int mi = 0; mi < 4; ++mi)
#pragma unroll
    for (int r = 0; r < 4; ++r) {
      const int slot = slotB + wr * 64 + mi * 16 + ql * 4 + r;
      const int tok = row_token[slot];      // 0 for pads (adds exact 0.0)
      const float p = row_scale[slot];
#pragma unroll
      for (int ni = 0; ni < 4; ++ni) {
        const int col = colBase + wc * 64 + ni * 16 + cl;
        float v = acc[mi][ni][r];
        if (ks == 0) v += p * w2b[e * 1024 + col];   // fold bias_init: sum over token's 2 experts
        atomicAdd(out + (size_t)tok * 1024 + col, v);
      }
    }
}

extern "C" void kernel_launch(void* const* d_in, const int* in_sizes, int n_in,
                              void* d_out, int out_size, void* d_ws, size_t ws_size,
                              hipStream_t stream) {
  const float* x   = (const float*)d_in[0];   // (2048, 1024)
  const float* rw  = (const float*)d_in[1];   // (8, 1024)
  const float* rb  = (const float*)d_in[2];   // (8,)
  const float* w1  = (const float*)d_in[3];   // (8, 1024, 2048)
  const float* w1b = (const float*)d_in[4];   // (8, 2048)
  const float* w2  = (const float*)d_in[5];   // (8, 1024, 1024)
  const float* w2b = (const float*)d_in[6];   // (8, 1024)
  float* out = (float*)d_out;                 // 2048*1024
  float* ew  = out + (size_t)2048 * 1024;     // 2048*2

  char* ws = (char*)d_ws;
  u16* xb        = (u16*)(ws);                                   //  4 MiB
  u16* w1t       = (u16*)(ws + (4ull << 20));                    // 32 MiB  (E, 2I, H)
  u16* w2t       = (u16*)(ws + (36ull << 20));                   // 16 MiB  (E, H, I)
  u16* actS      = (u16*)(ws + (52ull << 20));                   // 32 MiB  (8*2048 slots, 1024)
  int* row_token = (int*)(ws + (84ull << 20));                   // 64 KiB (16384)
  float* row_scale = (float*)(ws + (84ull << 20) + (64 << 10));  // 64 KiB
  int* cnt       = (int*)(ws + (84ull << 20) + (128 << 10));     // 32 B

  hipMemsetAsync(out, 0, (size_t)2048 * 1024 * 4, stream);            // gemm2 accumulates
  hipMemsetAsync(row_token, 0, (128 << 10) + 32, stream);             // tokens+scales+cnt = 0
  prep_kernel<<<13824, 256, 0, stream>>>(x, rw, rb, w1, w2, xb, w1t, w2t,
                                         ew, row_token, row_scale, cnt);
  gemm1_act_kernel<<<2048, 256, 0, stream>>>(xb, w1t, w1b, row_token, row_scale, cnt, actS);
  gemm2_add_kernel<<<2048, 256, 0, stream>>>(actS, w2t, w2b, row_token, row_scale, cnt, out);
}

// Round 5
// 330.077 us; speedup vs baseline: 1.2003x; 1.2003x over previous
//
#include <hip/hip_runtime.h>
#include <cstdint>
#include <cstddef>

typedef unsigned short u16;
typedef short bf16x8 __attribute__((ext_vector_type(8)));
typedef float floatx4 __attribute__((ext_vector_type(4)));

#define GLD16(gp, sp) __builtin_amdgcn_global_load_lds(                      \
    (const __attribute__((address_space(1))) void*)(gp),                     \
    (__attribute__((address_space(3))) void*)(sp), 16, 0, 0)

__device__ __forceinline__ u16 f2bf(float f) {
  unsigned u = __float_as_uint(f);
  u += 0x7fffu + ((u >> 16) & 1u);   // round-to-nearest-even
  return (u16)(u >> 16);
}

// ---------------- fused prep ----------------
// regions: [0,1024) cvt_x | [1024,5120) w1^T | [5120,7168) w2^T | [7168,7680) router+scatter
// transpose: 64r x 64c f32 tile, float2 global reads, ushort2 writes.
__global__ __launch_bounds__(256) void prep_kernel(
    const float* __restrict__ x, const float* __restrict__ rw, const float* __restrict__ rbias,
    const float* __restrict__ w1, const float* __restrict__ w2,
    u16* __restrict__ xb, u16* __restrict__ w1t, u16* __restrict__ w2t,
    float* __restrict__ ew, int* __restrict__ row_token, float* __restrict__ row_scale,
    int* __restrict__ cnt) {
  __shared__ float tile[64 * 66];
  const int b = blockIdx.x, tid = threadIdx.x;
  if (b < 1024) {                       // ---- x f32 -> bf16
    const float4* in4 = (const float4*)x;
    ushort4* out4 = (ushort4*)xb;
    int i = (b << 8) + tid;
#pragma unroll
    for (int rep = 0; rep < 2; ++rep, i += 262144) {
      float4 v = in4[i];
      ushort4 o;
      o.x = f2bf(v.x); o.y = f2bf(v.y); o.z = f2bf(v.z); o.w = f2bf(v.w);
      out4[i] = o;
    }
  } else if (b < 7168) {                // ---- weight transpose+cvt (64r x 64c tiles)
    const float* in; u16* out; int C, r0, c0;
    if (b < 5120) {
      int b2 = b - 1024, e = b2 >> 9, rem = b2 & 511;     // 16 r-tiles x 32 c-tiles
      C = 2048; r0 = (rem >> 5) << 6; c0 = (rem & 31) << 6;
      in = w1 + (size_t)e * 2097152; out = w1t + (size_t)e * 2097152;
    } else {
      int b2 = b - 5120, e = b2 >> 8, rem = b2 & 255;     // 16 r-tiles x 16 c-tiles
      C = 1024; r0 = (rem >> 4) << 6; c0 = (rem & 15) << 6;
      in = w2 + (size_t)e * 1048576; out = w2t + (size_t)e * 1048576;
    }
    const int tx = tid & 31, ty = tid >> 5;
#pragma unroll
    for (int k = 0; k < 8; ++k) {
      int row = k * 8 + ty;
      float2 v = *(const float2*)&in[(size_t)(r0 + row) * C + c0 + tx * 2];
      *(float2*)&tile[row * 66 + tx * 2] = v;
    }
    __syncthreads();
#pragma unroll
    for (int k = 0; k < 8; ++k) {
      int cc = k * 8 + ty;
      ushort2 v;
      v.x = f2bf(tile[(tx * 2) * 66 + cc]);
      v.y = f2bf(tile[(tx * 2 + 1) * 66 + cc]);
      *(ushort2*)(out + (size_t)(c0 + cc) * 1024 + r0 + tx * 2) = v;
    }
  } else {                              // ---- router (4 tokens/block) + direct scatter
    const int wave = tid >> 6, lane = tid & 63;
    const int t = ((b - 7168) << 2) + wave;
    const float4* xv = (const float4*)(x + (size_t)t * 1024);
    float acc[8];
#pragma unroll
    for (int e = 0; e < 8; ++e) acc[e] = 0.f;
    for (int j = lane; j < 256; j += 64) {
      float4 xx = xv[j];
#pragma unroll
      for (int e = 0; e < 8; ++e) {
        float4 wv = ((const float4*)(rw + (size_t)e * 1024))[j];
        acc[e] += xx.x * wv.x + xx.y * wv.y + xx.z * wv.z + xx.w * wv.w;
      }
    }
#pragma unroll
    for (int e = 0; e < 8; ++e) {
      float v = acc[e];
#pragma unroll
      for (int off = 32; off > 0; off >>= 1) v += __shfl_down(v, off);
      acc[e] = v;
    }
    if (lane == 0) {
      float p[8];
      float mx = -1e30f;
#pragma unroll
      for (int e = 0; e < 8; ++e) { p[e] = acc[e] + rbias[e]; mx = fmaxf(mx, p[e]); }
      float sum = 0.f;
#pragma unroll
      for (int e = 0; e < 8; ++e) { p[e] = __expf(p[e] - mx); sum += p[e]; }
      float inv = 1.f / sum;
#pragma unroll
      for (int e = 0; e < 8; ++e) p[e] *= inv;
      int i0 = 0;
#pragma unroll
      for (int e = 1; e < 8; ++e) if (p[e] > p[i0]) i0 = e;
      int i1 = (i0 == 0) ? 1 : 0;
#pragma unroll
      for (int e = 0; e < 8; ++e) if (e != i0 && e != i1 && p[e] > p[i1]) i1 = e;
      ew[t * 2 + 0] = p[i0];
      ew[t * 2 + 1] = p[i1];
      int s0 = atomicAdd(&cnt[i0], 1);           // fixed 2048-slot region per expert
      row_token[(i0 << 11) + s0] = t;
      row_scale[(i0 << 11) + s0] = p[i0];
      int s1 = atomicAdd(&cnt[i1], 1);
      row_token[(i1 << 11) + s1] = t;
      row_scale[(i1 << 11) + s1] = p[i1];
    }
  }
}

// ---------------- GEMM1: 128x128, BK=32, gathered rows, glu epilogue -> actS ----
// grid 2048: xcd=d&7, j=d>>3: colHi=j&1, rb=(j>>1)&15, e=j>>5; colIdx=xcd+8*colHi.
// LDS chunk-major: group g (16 rows x 32 k = 1 KiB) at g*512 u16;
// frag read = base + lane*8 u16 -> conflict-free ds_read_b128.
__global__ __launch_bounds__(256) void gemm1_act_kernel(
    const u16* __restrict__ xb, const u16* __restrict__ w1t,
    const float* __restrict__ w1b,
    const int* __restrict__ row_token, const float* __restrict__ row_scale,
    const int* __restrict__ cnt, u16* __restrict__ actS) {
  const int d = blockIdx.x;
  const int xcd = d & 7, j = d >> 3;
  const int colHi = j & 1, rb = (j >> 1) & 15, e = j >> 5;
  if (rb * 128 >= cnt[e]) return;
  const int colBase = (xcd + (colHi << 3)) << 7;
  const int slotB = (e << 11) + (rb << 7);
  __shared__ __align__(16) u16 As[4096];
  __shared__ __align__(16) u16 Bs[4096];
  const int tid = threadIdx.x, lane = tid & 63, wave = tid >> 6;
  const int row16 = lane & 15, chunk = lane >> 4;
  const u16* Bt = w1t + (size_t)e * 2097152;
  int tk0 = row_token[slotB + wave * 16 + row16];       if (tk0 < 0) tk0 = 0;
  int tk1 = row_token[slotB + (wave + 4) * 16 + row16]; if (tk1 < 0) tk1 = 0;
  const u16* aP0 = xb + (size_t)tk0 * 1024 + chunk * 8;
  const u16* aP1 = xb + (size_t)tk1 * 1024 + chunk * 8;
  const u16* bP0 = Bt + (size_t)(colBase + wave * 16 + row16) * 1024 + chunk * 8;
  const u16* bP1 = Bt + (size_t)(colBase + (wave + 4) * 16 + row16) * 1024 + chunk * 8;
  const int wr = wave >> 1, wc = wave & 1;
  floatx4 acc[4][4];
#pragma unroll
  for (int mi = 0; mi < 4; ++mi)
#pragma unroll
    for (int ni = 0; ni < 4; ++ni) acc[mi][ni] = floatx4{0.f, 0.f, 0.f, 0.f};

  for (int kt = 0; kt < 32; ++kt) {
    const int k = kt * 32;
    GLD16(aP0 + k, As + wave * 512);
    GLD16(aP1 + k, As + (wave + 4) * 512);
    GLD16(bP0 + k, Bs + wave * 512);
    GLD16(bP1 + k, Bs + (wave + 4) * 512);
    __syncthreads();
    bf16x8 af[4], bfr[4];
#pragma unroll
    for (int mi = 0; mi < 4; ++mi) af[mi] = *(const bf16x8*)(As + (wr * 4 + mi) * 512 + lane * 8);
#pragma unroll
    for (int ni = 0; ni < 4; ++ni) bfr[ni] = *(const bf16x8*)(Bs + (wc * 4 + ni) * 512 + lane * 8);
#pragma unroll
    for (int mi = 0; mi < 4; ++mi)
#pragma unroll
      for (int ni = 0; ni < 4; ++ni)
        acc[mi][ni] = __builtin_amdgcn_mfma_f32_16x16x32_bf16(af[mi], bfr[ni], acc[mi][ni], 0, 0, 0);
    __syncthreads();
  }

  const int cl = lane & 15, ql = lane >> 4;
#pragma unroll
  for (int mi = 0; mi < 4; ++mi) {
#pragma unroll
    for (int r = 0; r < 4; ++r) {
      const int slot = slotB + wr * 64 + mi * 16 + ql * 4 + r;
      const float c = row_scale[slot];  // 0 for padded slots -> zero fill of actS
#pragma unroll
      for (int ni = 0; ni < 4; ++ni) {
        const int n = colBase + wc * 64 + ni * 16 + cl;  // interleaved col of w1
        float v = acc[mi][ni][r] + w1b[e * 2048 + n];
        float o = __shfl_xor(v, 1);  // partner column
        if ((lane & 1) == 0) {       // even lane = gate col
          float g = fminf(v, 7.f);
          float u = fminf(fmaxf(o, -7.f), 7.f);
          float sg = 1.f / (1.f + __expf(-1.702f * g));
          float a = (u + 1.f) * (g * sg);
          actS[(size_t)slot * 1024 + (n >> 1)] = f2bf(c * a);
        }
      }
    }
  }
}

// ---------------- GEMM2: 128x128, BK=32, split-K=2, bias folded, pad-skip scatter ----
// grid 2048: xcd=d&7 (colIdx over 8 tiles), j=d>>3: ks=j&1, rb=(j>>1)&15, e=j>>5.
__global__ __launch_bounds__(256) void gemm2_add_kernel(
    const u16* __restrict__ actS, const u16* __restrict__ w2t, const float* __restrict__ w2b,
    const int* __restrict__ row_token, const float* __restrict__ row_scale,
    const int* __restrict__ cnt, float* __restrict__ out) {
  const int d = blockIdx.x;
  const int xcd = d & 7, j = d >> 3;
  const int ks = j & 1, rb = (j >> 1) & 15, e = j >> 5;
  if (rb * 128 >= cnt[e]) return;
  const int colBase = xcd << 7;
  const int slotB = (e << 11) + (rb << 7);
  const int k0 = ks << 9;
  __shared__ __align__(16) u16 As[4096];
  __shared__ __align__(16) u16 Bs[4096];
  const int tid = threadIdx.x, lane = tid & 63, wave = tid >> 6;
  const int row16 = lane & 15, chunk = lane >> 4;
  const u16* Bt = w2t + (size_t)e * 1048576;
  const u16* aP0 = actS + (size_t)(slotB + wave * 16 + row16) * 1024 + k0 + chunk * 8;
  const u16* aP1 = actS + (size_t)(slotB + (wave + 4) * 16 + row16) * 1024 + k0 + chunk * 8;
  const u16* bP0 = Bt + (size_t)(colBase + wave * 16 + row16) * 1024 + k0 + chunk * 8;
  const u16* bP1 = Bt + (size_t)(colBase + (wave + 4) * 16 + row16) * 1024 + k0 + chunk * 8;
  const int wr = wave >> 1, wc = wave & 1;
  floatx4 acc[4][4];
#pragma unroll
  for (int mi = 0; mi < 4; ++mi)
#pragma unroll
    for (int ni = 0; ni < 4; ++ni) acc[mi][ni] = floatx4{0.f, 0.f, 0.f, 0.f};

  for (int kt = 0; kt < 16; ++kt) {
    const int k = kt * 32;
    GLD16(aP0 + k, As + wave * 512);
    GLD16(aP1 + k, As + (wave + 4) * 512);
    GLD16(bP0 + k, Bs + wave * 512);
    GLD16(bP1 + k, Bs + (wave + 4) * 512);
    __syncthreads();
    bf16x8 af[4], bfr[4];
#pragma unroll
    for (int mi = 0; mi < 4; ++mi) af[mi] = *(const bf16x8*)(As + (wr * 4 + mi) * 512 + lane * 8);
#pragma unroll
    for (int ni = 0; ni < 4; ++ni) bfr[ni] = *(const bf16x8*)(Bs + (wc * 4 + ni) * 512 + lane * 8);
#pragma unroll
    for (int mi = 0; mi < 4; ++mi)
#pragma unroll
      for (int ni = 0; ni < 4; ++ni)
        acc[mi][ni] = __builtin_amdgcn_mfma_f32_16x16x32_bf16(af[mi], bfr[ni], acc[mi][ni], 0, 0, 0);
    __syncthreads();
  }

  const int cl = lane & 15, ql = lane >> 4;
#pragma unroll
  for (int mi = 0; mi < 4; ++mi)
#pragma unroll
    for (int r = 0; r < 4; ++r) {
      const int slot = slotB + wr * 64 + mi * 16 + ql * 4 + r;
      const int tok = row_token[slot];
      if (tok < 0) continue;               // SKIP pads — no atomic storm on token 0
      const float p = row_scale[slot];
#pragma unroll
      for (int ni = 0; ni < 4; ++ni) {
        const int col = colBase + wc * 64 + ni * 16 + cl;
        float v = acc[mi][ni][r];
        if (ks == 0) v += p * w2b[e * 1024 + col];   // bias fold (once per token-expert)
        atomicAdd(out + (size_t)tok * 1024 + col, v);
      }
    }
}

extern "C" void kernel_launch(void* const* d_in, const int* in_sizes, int n_in,
                              void* d_out, int out_size, void* d_ws, size_t ws_size,
                              hipStream_t stream) {
  const float* x   = (const float*)d_in[0];   // (2048, 1024)
  const float* rw  = (const float*)d_in[1];   // (8, 1024)
  const float* rb  = (const float*)d_in[2];   // (8,)
  const float* w1  = (const float*)d_in[3];   // (8, 1024, 2048)
  const float* w1b = (const float*)d_in[4];   // (8, 2048)
  const float* w2  = (const float*)d_in[5];   // (8, 1024, 1024)
  const float* w2b = (const float*)d_in[6];   // (8, 1024)
  float* out = (float*)d_out;                 // 2048*1024
  float* ew  = out + (size_t)2048 * 1024;     // 2048*2

  char* ws = (char*)d_ws;
  u16* xb        = (u16*)(ws);                                   //  4 MiB
  u16* w1t       = (u16*)(ws + (4ull << 20));                    // 32 MiB  (E, 2I, H)
  u16* w2t       = (u16*)(ws + (36ull << 20));                   // 16 MiB  (E, H, I)
  u16* actS      = (u16*)(ws + (52ull << 20));                   // 32 MiB  (8*2048 slots, 1024)
  int* row_token = (int*)(ws + (84ull << 20));                   // 64 KiB (16384)
  float* row_scale = (float*)(ws + (84ull << 20) + (64 << 10));  // 64 KiB
  int* cnt       = (int*)(ws + (84ull << 20) + (128 << 10));     // 32 B

  hipMemsetAsync(out, 0, (size_t)2048 * 1024 * 4, stream);       // gemm2 accumulates
  hipMemsetAsync(row_token, 0xFF, 64 << 10, stream);             // pads = -1
  hipMemsetAsync(row_scale, 0, (64 << 10) + 32, stream);         // scales + cnt = 0
  prep_kernel<<<7680, 256, 0, stream>>>(x, rw, rb, w1, w2, xb, w1t, w2t,
                                        ew, row_token, row_scale, cnt);
  gemm1_act_kernel<<<2048, 256, 0, stream>>>(xb, w1t, w1b, row_token, row_scale, cnt, actS);
  gemm2_add_kernel<<<2048, 256, 0, stream>>>(actS, w2t, w2b, row_token, row_scale, cnt, out);
}

// Round 6
// 303.912 us; speedup vs baseline: 1.3037x; 1.0861x over previous
//
#include <hip/hip_runtime.h>
#include <cstdint>
#include <cstddef>

typedef unsigned short u16;
typedef unsigned int u32;
typedef short bf16x8 __attribute__((ext_vector_type(8)));
typedef float floatx4 __attribute__((ext_vector_type(4)));

#define GLD16(gp, sp) __builtin_amdgcn_global_load_lds(                      \
    (const __attribute__((address_space(1))) void*)(gp),                     \
    (__attribute__((address_space(3))) void*)(sp), 16, 0, 0)

__device__ __forceinline__ u16 f2bf(float f) {
  unsigned u = __float_as_uint(f);
  u += 0x7fffu + ((u >> 16) & 1u);   // round-to-nearest-even
  return (u16)(u >> 16);
}

// ---------------- prep: x cvt + router (transposes eliminated) ----------------
// regions: [0,1024) cvt_x | [1024,1536) router+scatter
__global__ __launch_bounds__(256) void prep_kernel(
    const float* __restrict__ x, const float* __restrict__ rw, const float* __restrict__ rbias,
    u16* __restrict__ xb, float* __restrict__ ew,
    int* __restrict__ row_token, float* __restrict__ row_scale, int* __restrict__ cnt) {
  const int b = blockIdx.x, tid = threadIdx.x;
  if (b < 1024) {                       // ---- x f32 -> bf16
    const float4* in4 = (const float4*)x;
    ushort4* out4 = (ushort4*)xb;
    int i = (b << 8) + tid;
#pragma unroll
    for (int rep = 0; rep < 2; ++rep, i += 262144) {
      float4 v = in4[i];
      ushort4 o;
      o.x = f2bf(v.x); o.y = f2bf(v.y); o.z = f2bf(v.z); o.w = f2bf(v.w);
      out4[i] = o;
    }
  } else {                              // ---- router (4 tokens/block) + direct scatter
    const int wave = tid >> 6, lane = tid & 63;
    const int t = ((b - 1024) << 2) + wave;
    const float4* xv = (const float4*)(x + (size_t)t * 1024);
    float acc[8];
#pragma unroll
    for (int e = 0; e < 8; ++e) acc[e] = 0.f;
    for (int j = lane; j < 256; j += 64) {
      float4 xx = xv[j];
#pragma unroll
      for (int e = 0; e < 8; ++e) {
        float4 wv = ((const float4*)(rw + (size_t)e * 1024))[j];
        acc[e] += xx.x * wv.x + xx.y * wv.y + xx.z * wv.z + xx.w * wv.w;
      }
    }
#pragma unroll
    for (int e = 0; e < 8; ++e) {
      float v = acc[e];
#pragma unroll
      for (int off = 32; off > 0; off >>= 1) v += __shfl_down(v, off);
      acc[e] = v;
    }
    if (lane == 0) {
      float p[8];
      float mx = -1e30f;
#pragma unroll
      for (int e = 0; e < 8; ++e) { p[e] = acc[e] + rbias[e]; mx = fmaxf(mx, p[e]); }
      float sum = 0.f;
#pragma unroll
      for (int e = 0; e < 8; ++e) { p[e] = __expf(p[e] - mx); sum += p[e]; }
      float inv = 1.f / sum;
#pragma unroll
      for (int e = 0; e < 8; ++e) p[e] *= inv;
      int i0 = 0;
#pragma unroll
      for (int e = 1; e < 8; ++e) if (p[e] > p[i0]) i0 = e;
      int i1 = (i0 == 0) ? 1 : 0;
#pragma unroll
      for (int e = 0; e < 8; ++e) if (e != i0 && e != i1 && p[e] > p[i1]) i1 = e;
      ew[t * 2 + 0] = p[i0];
      ew[t * 2 + 1] = p[i1];
      int s0 = atomicAdd(&cnt[i0], 1);           // fixed 2048-slot region per expert
      row_token[(i0 << 11) + s0] = t;
      row_scale[(i0 << 11) + s0] = p[i0];
      int s1 = atomicAdd(&cnt[i1], 1);
      row_token[(i1 << 11) + s1] = t;
      row_scale[(i1 << 11) + s1] = p[i1];
    }
  }
}

// B-stage helper: read 8 f32 k-rows for one col n from (K,N)-major weights,
// cvt+pack, single conflict-free ds_write_b128 into chunk-major bf16 layout.
// idx in [0,512): n = idx&127 (col within tile), q = idx>>7 (k-quad).
__device__ __forceinline__ void stage_bt(const float* __restrict__ src0, int C, int idx,
                                         u16* __restrict__ Bs) {
  const int n = idx & 127, q = idx >> 7;
  const float* src = src0 + (size_t)(q * 8) * C + n;
  float f[8];
#pragma unroll
  for (int j = 0; j < 8; ++j) f[j] = src[(size_t)j * C];
  u32 pk[4];
#pragma unroll
  for (int m = 0; m < 4; ++m) pk[m] = (u32)f2bf(f[2 * m]) | ((u32)f2bf(f[2 * m + 1]) << 16);
  *(uint4*)(Bs + ((n >> 4) << 9) + (q << 7) + ((n & 15) << 3)) =
      make_uint4(pk[0], pk[1], pk[2], pk[3]);
}

// ---------------- GEMM1: 128x128, BK=32, gathered rows, in-kernel B-transpose ----
// grid 2048: xcd=d&7, j=d>>3: colHi=j&1, rb=(j>>1)&15, e=j>>5; colIdx=xcd+8*colHi.
// LDS chunk-major: group g (16 rows x 32 k = 1 KiB) at g*512 u16;
// frag read/write = slab base + lane*16B -> conflict-free.
__global__ __launch_bounds__(256) void gemm1_act_kernel(
    const u16* __restrict__ xb, const float* __restrict__ w1,
    const float* __restrict__ w1b,
    const int* __restrict__ row_token, const float* __restrict__ row_scale,
    const int* __restrict__ cnt, u16* __restrict__ actS) {
  const int d = blockIdx.x;
  const int xcd = d & 7, j = d >> 3;
  const int colHi = j & 1, rb = (j >> 1) & 15, e = j >> 5;
  if (rb * 128 >= cnt[e]) return;
  const int colBase = (xcd + (colHi << 3)) << 7;
  const int slotB = (e << 11) + (rb << 7);
  __shared__ __align__(16) u16 As[4096];
  __shared__ __align__(16) u16 Bs[4096];
  const int tid = threadIdx.x, lane = tid & 63, wave = tid >> 6;
  const int row16 = lane & 15, chunk = lane >> 4;
  const float* w1e = w1 + (size_t)e * 2097152 + colBase;   // f32 (1024 k x 2048 n)
  int tk0 = row_token[slotB + wave * 16 + row16];       if (tk0 < 0) tk0 = 0;
  int tk1 = row_token[slotB + (wave + 4) * 16 + row16]; if (tk1 < 0) tk1 = 0;
  const u16* aP0 = xb + (size_t)tk0 * 1024 + chunk * 8;
  const u16* aP1 = xb + (size_t)tk1 * 1024 + chunk * 8;
  const int wr = wave >> 1, wc = wave & 1;
  floatx4 acc[4][4];
#pragma unroll
  for (int mi = 0; mi < 4; ++mi)
#pragma unroll
    for (int ni = 0; ni < 4; ++ni) acc[mi][ni] = floatx4{0.f, 0.f, 0.f, 0.f};

  for (int kt = 0; kt < 32; ++kt) {
    const int k = kt * 32;
    GLD16(aP0 + k, As + wave * 512);
    GLD16(aP1 + k, As + (wave + 4) * 512);
    stage_bt(w1e + (size_t)k * 2048, 2048, tid, Bs);
    stage_bt(w1e + (size_t)k * 2048, 2048, tid + 256, Bs);
    __syncthreads();
    bf16x8 af[4], bfr[4];
#pragma unroll
    for (int mi = 0; mi < 4; ++mi) af[mi] = *(const bf16x8*)(As + (wr * 4 + mi) * 512 + lane * 8);
#pragma unroll
    for (int ni = 0; ni < 4; ++ni) bfr[ni] = *(const bf16x8*)(Bs + (wc * 4 + ni) * 512 + lane * 8);
#pragma unroll
    for (int mi = 0; mi < 4; ++mi)
#pragma unroll
      for (int ni = 0; ni < 4; ++ni)
        acc[mi][ni] = __builtin_amdgcn_mfma_f32_16x16x32_bf16(af[mi], bfr[ni], acc[mi][ni], 0, 0, 0);
    __syncthreads();
  }

  const int cl = lane & 15, ql = lane >> 4;
#pragma unroll
  for (int mi = 0; mi < 4; ++mi) {
#pragma unroll
    for (int r = 0; r < 4; ++r) {
      const int slot = slotB + wr * 64 + mi * 16 + ql * 4 + r;
      const float c = row_scale[slot];  // 0 for padded slots -> zero fill of actS
#pragma unroll
      for (int ni = 0; ni < 4; ++ni) {
        const int n = colBase + wc * 64 + ni * 16 + cl;  // interleaved col of w1
        float v = acc[mi][ni][r] + w1b[e * 2048 + n];
        float o = __shfl_xor(v, 1);  // partner column
        if ((lane & 1) == 0) {       // even lane = gate col
          float g = fminf(v, 7.f);
          float u = fminf(fmaxf(o, -7.f), 7.f);
          float sg = 1.f / (1.f + __expf(-1.702f * g));
          float a = (u + 1.f) * (g * sg);
          actS[(size_t)slot * 1024 + (n >> 1)] = f2bf(c * a);
        }
      }
    }
  }
}

// ---------------- GEMM2: 128x128, BK=32, split-K=2, in-kernel B-transpose ----
// grid 2048: xcd=d&7 (colIdx over 8 tiles), j=d>>3: ks=j&1, rb=(j>>1)&15, e=j>>5.
__global__ __launch_bounds__(256) void gemm2_add_kernel(
    const u16* __restrict__ actS, const float* __restrict__ w2, const float* __restrict__ w2b,
    const int* __restrict__ row_token, const float* __restrict__ row_scale,
    const int* __restrict__ cnt, float* __restrict__ out) {
  const int d = blockIdx.x;
  const int xcd = d & 7, j = d >> 3;
  const int ks = j & 1, rb = (j >> 1) & 15, e = j >> 5;
  if (rb * 128 >= cnt[e]) return;
  const int colBase = xcd << 7;
  const int slotB = (e << 11) + (rb << 7);
  const int k0 = ks << 9;
  __shared__ __align__(16) u16 As[4096];
  __shared__ __align__(16) u16 Bs[4096];
  const int tid = threadIdx.x, lane = tid & 63, wave = tid >> 6;
  const int row16 = lane & 15, chunk = lane >> 4;
  const float* w2e = w2 + (size_t)e * 1048576 + (size_t)k0 * 1024 + colBase;  // f32 (1024 i x 1024 h)
  const u16* aP0 = actS + (size_t)(slotB + wave * 16 + row16) * 1024 + k0 + chunk * 8;
  const u16* aP1 = actS + (size_t)(slotB + (wave + 4) * 16 + row16) * 1024 + k0 + chunk * 8;
  const int wr = wave >> 1, wc = wave & 1;
  floatx4 acc[4][4];
#pragma unroll
  for (int mi = 0; mi < 4; ++mi)
#pragma unroll
    for (int ni = 0; ni < 4; ++ni) acc[mi][ni] = floatx4{0.f, 0.f, 0.f, 0.f};

  for (int kt = 0; kt < 16; ++kt) {
    const int k = kt * 32;
    GLD16(aP0 + k, As + wave * 512);
    GLD16(aP1 + k, As + (wave + 4) * 512);
    stage_bt(w2e + (size_t)k * 1024, 1024, tid, Bs);
    stage_bt(w2e + (size_t)k * 1024, 1024, tid + 256, Bs);
    __syncthreads();
    bf16x8 af[4], bfr[4];
#pragma unroll
    for (int mi = 0; mi < 4; ++mi) af[mi] = *(const bf16x8*)(As + (wr * 4 + mi) * 512 + lane * 8);
#pragma unroll
    for (int ni = 0; ni < 4; ++ni) bfr[ni] = *(const bf16x8*)(Bs + (wc * 4 + ni) * 512 + lane * 8);
#pragma unroll
    for (int mi = 0; mi < 4; ++mi)
#pragma unroll
      for (int ni = 0; ni < 4; ++ni)
        acc[mi][ni] = __builtin_amdgcn_mfma_f32_16x16x32_bf16(af[mi], bfr[ni], acc[mi][ni], 0, 0, 0);
    __syncthreads();
  }

  const int cl = lane & 15, ql = lane >> 4;
#pragma unroll
  for (int mi = 0; mi < 4; ++mi)
#pragma unroll
    for (int r = 0; r < 4; ++r) {
      const int slot = slotB + wr * 64 + mi * 16 + ql * 4 + r;
      const int tok = row_token[slot];
      if (tok < 0) continue;               // skip pads — no atomic storm
      const float p = row_scale[slot];
#pragma unroll
      for (int ni = 0; ni < 4; ++ni) {
        const int col = colBase + wc * 64 + ni * 16 + cl;
        float v = acc[mi][ni][r];
        if (ks == 0) v += p * w2b[e * 1024 + col];   // bias fold (once per token-expert)
        atomicAdd(out + (size_t)tok * 1024 + col, v);
      }
    }
}

extern "C" void kernel_launch(void* const* d_in, const int* in_sizes, int n_in,
                              void* d_out, int out_size, void* d_ws, size_t ws_size,
                              hipStream_t stream) {
  const float* x   = (const float*)d_in[0];   // (2048, 1024)
  const float* rw  = (const float*)d_in[1];   // (8, 1024)
  const float* rb  = (const float*)d_in[2];   // (8,)
  const float* w1  = (const float*)d_in[3];   // (8, 1024, 2048)
  const float* w1b = (const float*)d_in[4];   // (8, 2048)
  const float* w2  = (const float*)d_in[5];   // (8, 1024, 1024)
  const float* w2b = (const float*)d_in[6];   // (8, 1024)
  float* out = (float*)d_out;                 // 2048*1024
  float* ew  = out + (size_t)2048 * 1024;     // 2048*2

  char* ws = (char*)d_ws;
  u16* xb          = (u16*)(ws);                                 //  4 MiB
  u16* actS        = (u16*)(ws + (4ull << 20));                  // 32 MiB (8*2048 slots, 1024)
  int* row_token   = (int*)(ws + (36ull << 20));                 // 64 KiB (16384)
  float* row_scale = (float*)(ws + (36ull << 20) + (64 << 10));  // 64 KiB
  int* cnt         = (int*)(ws + (36ull << 20) + (128 << 10));   // 32 B

  hipMemsetAsync(out, 0, (size_t)2048 * 1024 * 4, stream);       // gemm2 accumulates
  hipMemsetAsync(row_token, 0xFF, 64 << 10, stream);             // pads = -1
  hipMemsetAsync(row_scale, 0, (64 << 10) + 32, stream);         // scales + cnt = 0
  prep_kernel<<<1536, 256, 0, stream>>>(x, rw, rb, xb, ew, row_token, row_scale, cnt);
  gemm1_act_kernel<<<2048, 256, 0, stream>>>(xb, w1, w1b, row_token, row_scale, cnt, actS);
  gemm2_add_kernel<<<2048, 256, 0, stream>>>(actS, w2, w2b, row_token, row_scale, cnt, out);
}